// Round 19
// baseline (122.807 us; speedup 1.0000x reference)
//
#include <hip/hip_runtime.h>
#include <hip/hip_bf16.h>
#include <hip/hip_fp16.h>

typedef __attribute__((ext_vector_type(8))) short short8;
typedef __attribute__((ext_vector_type(4))) float f32x4;
typedef _Float16 h2v __attribute__((ext_vector_type(2)));
typedef _Float16 h8v __attribute__((ext_vector_type(8)));
typedef unsigned short ushort_t;

namespace {

constexpr int H     = 128;
constexpr int E     = 1000000;
constexpr int NNODE = 100000;
constexpr int EB    = 512;                   // edges per tile (8 waves x 64)
constexpr int NTILE = (E + EB - 1) / EB;     // 1954
constexpr int GRID  = 256;                   // persistent: 1 block per CU
constexpr int TPB   = NTILE / GRID;          // 7
constexpr int REM   = NTILE - TPB * GRID;    // 162

// d_ws layout: atab fp16 [NNODE][256] (Ai+b1 | Aj), then W1(bf16)/W2(fp16) frag tables
constexpr size_t AT_OFF  = 0;
constexpr size_t AT_SZ   = (size_t)NNODE * 256 * 2;   // 51,200,000 B
constexpr size_t W1F_OFF = AT_SZ;
constexpr size_t W1F_SZ  = 64 * 64 * 8 * 2;           // 65536 B
constexpr size_t W2F_OFF = W1F_OFF + W1F_SZ;
constexpr size_t W2F_SZ  = 20 * 64 * 8 * 2;           // 20480 B
constexpr size_t WS_NEED = W2F_OFF + W2F_SZ;

__device__ __forceinline__ ushort_t f2bf(float x) {
    unsigned u = __float_as_uint(x);
    return (ushort_t)((u + 0x7FFFu + ((u >> 16) & 1u)) >> 16);
}
__device__ __forceinline__ unsigned pkbf(float a, float b) {
    __hip_bfloat162 t = __float22bfloat162_rn(make_float2(a, b));
    return *reinterpret_cast<unsigned*>(&t);
}
__device__ __forceinline__ unsigned pkhf(float a, float b) {
    __half2 t = __float22half2_rn(make_float2(a, b));
    return *reinterpret_cast<unsigned*>(&t);
}
__device__ __forceinline__ int imin(int a, int b) { return a < b ? a : b; }

union FragU { int4 i; short8 s; };
union SlotU { short8 s; h2v h[4]; };
union H8U   { h8v v; h2v h[4]; int4 i; };
union U32H  { unsigned u; h2v h; };

typedef const __attribute__((address_space(1))) unsigned int* gptr_t;
typedef __attribute__((address_space(3))) unsigned int* lptr_t;

__device__ __forceinline__ void gload16(const void* g, void* l) {
    __builtin_amdgcn_global_load_lds((gptr_t)g, (lptr_t)l, 16, 0, 0);
}

// ---- prep 1: W1 (rows 0..255, bf16 for build_atab) / W2ext (K=160, fp16) ----
__global__ void cvt_wfrag(const float* __restrict__ W1, const float* __restrict__ W2,
                          const float* __restrict__ b2,
                          ushort_t* __restrict__ w1f, ushort_t* __restrict__ w2f) {
    int u = blockIdx.x, l = threadIdx.x;
    int lo = l & 15, hi = l >> 4;
    if (u < 64) {
        int s = u >> 3, n = u & 7, col = n * 16 + lo;
#pragma unroll
        for (int j = 0; j < 8; ++j) {
            int kk = s * 32 + hi * 8 + j;
            w1f[(u * 64 + l) * 8 + j] = f2bf(W1[kk * 128 + col]);
        }
    } else {
        int u2 = u - 64;
        int s = u2 >> 2, n = u2 & 3, col = n * 16 + lo;
#pragma unroll
        for (int j = 0; j < 8; ++j) {
            int kk = s * 32 + hi * 8 + j;
            float v = (kk < 128) ? W2[kk * 64 + col]
                    : (kk == 128 ? b2[col] : 0.f);
            __half hh = __float2half_rn(v);
            w2f[(u2 * 64 + l) * 8 + j] = *reinterpret_cast<ushort_t*>(&hh);
        }
    }
}

// ---- prep 2: A-tables. Ai = node.W1[0:128] + b1 (folded), Aj = node.W1[128:256] ----
struct PrepSm { ushort_t w1f[32768]; };

__global__ __launch_bounds__(512, 2)
void build_atab(const float* __restrict__ ne, const ushort_t* __restrict__ w1fg,
                const float* __restrict__ b1, ushort_t* __restrict__ atab) {
    __shared__ PrepSm sm;
    const int tid = threadIdx.x;
    {
        const uint4* s1 = reinterpret_cast<const uint4*>(w1fg);
        uint4*       d1 = reinterpret_cast<uint4*>(sm.w1f);
#pragma unroll
        for (int i = 0; i < 8; ++i) d1[i * 512 + tid] = s1[i * 512 + tid];
    }
    __syncthreads();

    const int wid = tid >> 6, lane = tid & 63;
    const int lo = lane & 15, hi = lane >> 4;
    const int nbase = blockIdx.x * 512 + wid * 64;
    const f32x4 z4 = {0.f, 0.f, 0.f, 0.f};

    short8 nf[4][4];
#pragma unroll
    for (int mt = 0; mt < 4; ++mt) {
        int node = imin(nbase + mt * 16 + lo, NNODE - 1);
        const float* row = ne + (size_t)node * H;
#pragma unroll
        for (int s = 0; s < 4; ++s) {
            f32x4 a = *reinterpret_cast<const f32x4*>(row + s * 32 + hi * 8);
            f32x4 b = *reinterpret_cast<const f32x4*>(row + s * 32 + hi * 8 + 4);
            FragU f;
            f.i = make_int4((int)pkbf(a[0], a[1]), (int)pkbf(a[2], a[3]),
                            (int)pkbf(b[0], b[1]), (int)pkbf(b[2], b[3]));
            nf[mt][s] = f.s;
        }
    }

#pragma unroll
    for (int X = 0; X < 2; ++X) {
        f32x4 acc[4][8];
        if (X == 0) {
#pragma unroll
            for (int n = 0; n < 8; ++n) {
                f32x4 b1v = *reinterpret_cast<const f32x4*>(b1 + n * 16 + hi * 4);
#pragma unroll
                for (int mt = 0; mt < 4; ++mt) acc[mt][n] = b1v;
            }
        } else {
#pragma unroll
            for (int mt = 0; mt < 4; ++mt)
#pragma unroll
                for (int n = 0; n < 8; ++n) acc[mt][n] = z4;
        }
#pragma unroll
        for (int s = 0; s < 4; ++s)
#pragma unroll
            for (int n = 0; n < 8; ++n) {
                short8 wa = *reinterpret_cast<const short8*>(
                    sm.w1f + (((X * 4 + s) * 8 + n) * 64 + lane) * 8);
#pragma unroll
                for (int mt = 0; mt < 4; ++mt)
                    acc[mt][n] = __builtin_amdgcn_mfma_f32_16x16x32_bf16(wa, nf[mt][s], acc[mt][n], 0, 0, 0);
            }
#pragma unroll
        for (int mt = 0; mt < 4; ++mt) {
            int node = nbase + mt * 16 + lo;
            if (node < NNODE) {
                ushort_t* dst = atab + (size_t)node * 256 + X * 128;
#pragma unroll
                for (int n = 0; n < 8; ++n) {
                    uint2 v = make_uint2(pkhf(acc[mt][n][0], acc[mt][n][1]),
                                         pkhf(acc[mt][n][2], acc[mt][n][3]));
                    *reinterpret_cast<uint2*>(dst + n * 16 + hi * 4) = v;
                }
            }
        }
    }
}

// ---- main persistent kernel: LDS-ring gather + packed-fp16 + phase-interleave ----
struct __align__(16) SmemT {
    char     gbuf[8][2][8192];           // 131072 B : per-wave 2-slot ring
    ushort_t w2f[10240];                 // 20480 B (fp16)
    unsigned t0h[64], t1h[64], gh[64], bh[64];   // packed half2 params, 1 KB
    float    w3s[64];                    // 256 B
};                                       // ~152.6 KB

// issue one subtile's 8 gathers (i then j slices) into `slotp`
#define GISSUE(slotp, iv, jv)                                                   \
    {                                                                           \
        const ushort_t* gi_ = atab + (size_t)(iv) * 256 + hi * 8;               \
        const ushort_t* gj_ = atab + (size_t)(jv) * 256 + 128 + hi * 8;         \
        char* lb_ = (slotp);                                                    \
        _Pragma("unroll")                                                       \
        for (int s_ = 0; s_ < 4; ++s_) gload16(gi_ + s_ * 32, lb_ + s_ * 1024); \
        _Pragma("unroll")                                                       \
        for (int s_ = 0; s_ < 4; ++s_) gload16(gj_ + s_ * 32, lb_ + 4096 + s_ * 1024); \
    }

// WAR fence + re-issue gathers into the just-consumed slot
#define GFI(slotp, IV, JV)                                                      \
    asm volatile("s_waitcnt lgkmcnt(0)" ::: "memory");                          \
    __builtin_amdgcn_sched_barrier(0);                                          \
    GISSUE(slotp, IV, JV);

// A-phase: wait for slot, read it, compute packed x + raw stats into set SET
#define SUBA(SET, MT, slotp, WAITLIT)                                           \
    asm volatile("s_waitcnt " WAITLIT ::: "memory");                            \
    __builtin_amdgcn_sched_barrier(0);                                          \
    {                                                                           \
        const _Float16 axs = (_Float16)av[MT].x;                                \
        const _Float16 ays = (_Float16)av[MT].y;                                \
        const h2v ax2 = {axs, axs};                                             \
        const h2v ay2 = {ays, ays};                                             \
        float s1t = 0.f, s2t = 0.f;                                             \
        _Pragma("unroll")                                                       \
        for (int s = 0; s < 4; ++s) {                                           \
            SlotU ui, uj;                                                       \
            ui.s = *reinterpret_cast<const short8*>((slotp) + s * 1024 + lane * 16);        \
            uj.s = *reinterpret_cast<const short8*>((slotp) + 4096 + s * 1024 + lane * 16); \
            uint4 t0p = *reinterpret_cast<const uint4*>(sm.t0h + s * 16 + hi * 4); \
            uint4 t1p = *reinterpret_cast<const uint4*>(sm.t1h + s * 16 + hi * 4); \
            const unsigned t0a[4] = {t0p.x, t0p.y, t0p.z, t0p.w};               \
            const unsigned t1a[4] = {t1p.x, t1p.y, t1p.z, t1p.w};               \
            _Pragma("unroll")                                                   \
            for (int p = 0; p < 4; ++p) {                                       \
                U32H w0; w0.u = t0a[p];                                         \
                U32H w1; w1.u = t1a[p];                                         \
                h2v t = ui.h[p] + uj.h[p];                                      \
                t = __builtin_elementwise_fma(ax2, w0.h, t);                    \
                t = __builtin_elementwise_fma(ay2, w1.h, t);                    \
                x2_##SET[s][p] = t;                                             \
                s1t = __builtin_amdgcn_fdot2(t, one2, s1t, false);              \
                s2t = __builtin_amdgcn_fdot2(t, t, s2t, false);                 \
            }                                                                   \
        }                                                                       \
        s1_##SET = s1t; s2_##SET = s2t;                                         \
    }

// B-phase: LN finalize, h pack, GEMM2 MFMA, W3 epilogue, store
#define SUBB(SET, MT)                                                           \
    {                                                                           \
        float a_ = s1_##SET, b_ = s2_##SET;                                     \
        a_ += __shfl_xor(a_, 16); a_ += __shfl_xor(a_, 32);                     \
        b_ += __shfl_xor(b_, 16); b_ += __shfl_xor(b_, 32);                     \
        float mean = a_ * (1.f / 128.f);                                        \
        float var  = b_ * (1.f / 128.f) - mean * mean;                          \
        float rstd = rsqrtf(var + 1e-5f);                                       \
        const _Float16 rs_ = (_Float16)rstd;                                    \
        const _Float16 cs_ = (_Float16)(-mean * rstd);                          \
        const h2v rs2 = {rs_, rs_};                                             \
        const h2v cs2 = {cs_, cs_};                                             \
        h8v hfr[4];                                                             \
        _Pragma("unroll")                                                       \
        for (int s = 0; s < 4; ++s) {                                           \
            uint4 gp = *reinterpret_cast<const uint4*>(sm.gh + s * 16 + hi * 4); \
            uint4 bp = *reinterpret_cast<const uint4*>(sm.bh + s * 16 + hi * 4); \
            const unsigned ga[4] = {gp.x, gp.y, gp.z, gp.w};                    \
            const unsigned ba[4] = {bp.x, bp.y, bp.z, bp.w};                    \
            H8U f;                                                              \
            _Pragma("unroll")                                                   \
            for (int p = 0; p < 4; ++p) {                                       \
                U32H g_; g_.u = ga[p];                                          \
                U32H bb_; bb_.u = ba[p];                                        \
                h2v t = __builtin_elementwise_fma(x2_##SET[s][p], rs2, cs2);    \
                t = __builtin_elementwise_fma(t, g_.h, bb_.h);                  \
                t = __builtin_elementwise_max(t, zero2);                        \
                f.h[p] = t;                                                     \
            }                                                                   \
            hfr[s] = f.v;                                                       \
        }                                                                       \
        f32x4 a2[4];                                                            \
        _Pragma("unroll")                                                       \
        for (int n2 = 0; n2 < 4; ++n2) a2[n2] = zero4;                          \
        __builtin_amdgcn_s_setprio(1);                                          \
        _Pragma("unroll")                                                       \
        for (int s = 0; s < 4; ++s) {                                           \
            _Pragma("unroll")                                                   \
            for (int n2 = 0; n2 < 4; ++n2) {                                    \
                h8v wa = *reinterpret_cast<const h8v*>(sm.w2f + ((s * 4 + n2) * 64 + lane) * 8); \
                a2[n2] = __builtin_amdgcn_mfma_f32_16x16x32_f16(wa, hfr[s], a2[n2], 0, 0, 0); \
            }                                                                   \
        }                                                                       \
        {                                                                       \
            H8U cf; cf.i = make_int4(hi == 0 ? 0x00003C00 : 0, 0, 0, 0);        \
            _Pragma("unroll")                                                   \
            for (int n2 = 0; n2 < 4; ++n2) {                                    \
                h8v wa = *reinterpret_cast<const h8v*>(sm.w2f + ((16 + n2) * 64 + lane) * 8); \
                a2[n2] = __builtin_amdgcn_mfma_f32_16x16x32_f16(wa, cf.v, a2[n2], 0, 0, 0);   \
            }                                                                   \
        }                                                                       \
        __builtin_amdgcn_s_setprio(0);                                          \
        float part = 0.f;                                                       \
        _Pragma("unroll")                                                       \
        for (int n2 = 0; n2 < 4; ++n2) {                                        \
            f32x4 w3v = *reinterpret_cast<const f32x4*>(sm.w3s + n2 * 16 + hi * 4); \
            _Pragma("unroll")                                                   \
            for (int r = 0; r < 4; ++r)                                         \
                part = fmaf(fmaxf(a2[n2][r], 0.f), w3v[r], part);               \
        }                                                                       \
        part += __shfl_xor(part, 16);                                           \
        part += __shfl_xor(part, 32);                                           \
        if (hi == 0) {                                                          \
            int e = tb + (MT) * 16 + lo;                                        \
            if (e < E) out[e] = part + b3s;                                     \
        }                                                                       \
    }

__global__ __launch_bounds__(512, 2)
void edge_mlp_mfma(const ushort_t* __restrict__ atab,
                   const ushort_t* __restrict__ w2fg,
                   const int*      __restrict__ eidx,   // [2][E] int32
                   const float*    __restrict__ attr,   // [E][2]
                   const float*    __restrict__ W1,     // rows 256/257 (attr rows)
                   const float*    __restrict__ gamma_,
                   const float*    __restrict__ beta_,
                   const float*    __restrict__ W3,
                   const float*    __restrict__ b3,
                   float*          __restrict__ out) {
    __shared__ SmemT sm;
    const int tid = threadIdx.x;
    const int bid = blockIdx.x;

    {
        const uint4* s2 = reinterpret_cast<const uint4*>(w2fg);
        uint4*       d2 = reinterpret_cast<uint4*>(sm.w2f);
        for (int i = tid; i < 1280; i += 512) d2[i] = s2[i];
    }
    if (tid < 64) {
        sm.t0h[tid] = pkhf(W1[256 * H + 2 * tid], W1[256 * H + 2 * tid + 1]);
        sm.t1h[tid] = pkhf(W1[257 * H + 2 * tid], W1[257 * H + 2 * tid + 1]);
        sm.gh[tid]  = pkhf(gamma_[2 * tid], gamma_[2 * tid + 1]);
        sm.bh[tid]  = pkhf(beta_[2 * tid], beta_[2 * tid + 1]);
        sm.w3s[tid] = W3[tid];
    }
    __syncthreads();   // drains all counters: clean vmcnt slate per wave

    const int wid = tid >> 6;
    const int lane = tid & 63;
    const int lo = lane & 15, hi = lane >> 4;
    const int ebl = wid * 64;
    const int nk = (bid < REM) ? TPB + 1 : TPB;
    char* slot0 = sm.gbuf[wid][0];
    char* slot1 = sm.gbuf[wid][1];
    const float2* attr2 = reinterpret_cast<const float2*>(attr);
    const float b3s = b3[0];
    const f32x4 zero4 = {0.f, 0.f, 0.f, 0.f};
    const h2v one2  = {(_Float16)1.f, (_Float16)1.f};
    const h2v zero2 = {(_Float16)0.f, (_Float16)0.f};

    int ci[4], cj[4], ni[4], nj[4];
    float2 av[4], avn[4];

    // per-subtile register sets (static names; rule #20)
    h2v x2_0[4][4], x2_1[4][4], x2_2[4][4], x2_3[4][4];
    float s1_0, s2_0, s1_1, s2_1, s1_2, s2_2, s1_3, s2_3;

    // ---- prologue: tile-0 indices (sync), g(0), g(1), tile-1 indices (async) ----
    {
        int tb0 = bid * EB + ebl;
#pragma unroll
        for (int mt = 0; mt < 4; ++mt) {
            int e = imin(tb0 + mt * 16 + lo, E - 1);
            ci[mt] = eidx[e]; cj[mt] = eidx[E + e];
            av[mt] = attr2[e];
        }
    }
    GISSUE(slot0, ci[0], cj[0]);
    GISSUE(slot1, ci[1], cj[1]);
    {
        int tb1 = (bid + imin(1, nk - 1) * GRID) * EB + ebl;
#pragma unroll
        for (int mt = 0; mt < 4; ++mt) {
            int e = imin(tb1 + mt * 16 + lo, E - 1);
            ni[mt] = eidx[e]; nj[mt] = eidx[E + e];
            avn[mt] = attr2[e];
        }
    }
    // queue at loop entry: g_slot0(8), g_slot1(8), idx(12) = 28

    for (int k = 0; k < nk; ++k) {
        const int tb = (bid + k * GRID) * EB + ebl;

        // A0/A1: consume slots, reissue for subtiles 2/3 of THIS tile
        SUBA(0, 0, slot0, "vmcnt(20)");
        GFI(slot0, ci[2], cj[2]);
        SUBA(1, 1, slot1, "vmcnt(20)");
        GFI(slot1, ci[3], cj[3]);

        // A2 ∥ B0 : B0's serial LN chain fills A2's load shadow (same fence region)
        SUBA(2, 2, slot0, "vmcnt(8)");
        SUBB(0, 0);
        GFI(slot0, ni[0], nj[0]);

        // A3 ∥ B1
        SUBA(3, 3, slot1, "vmcnt(8)");
        SUBB(1, 1);
        GFI(slot1, ni[1], nj[1]);

        // rotate index state; load tile k+2's indices (12 VMEM, youngest in queue)
#pragma unroll
        for (int mt = 0; mt < 4; ++mt) { ci[mt] = ni[mt]; cj[mt] = nj[mt]; av[mt] = avn[mt]; }
        {
            int t2 = imin(k + 2, nk - 1);
            int tb2 = (bid + t2 * GRID) * EB + ebl;
#pragma unroll
            for (int mt = 0; mt < 4; ++mt) {
                int e = imin(tb2 + mt * 16 + lo, E - 1);
                ni[mt] = eidx[e]; nj[mt] = eidx[E + e];
                avn[mt] = attr2[e];
            }
        }

        SUBB(2, 2);
        SUBB(3, 3);
    }
}

} // namespace

extern "C" void kernel_launch(void* const* d_in, const int* in_sizes, int n_in,
                              void* d_out, int out_size, void* d_ws, size_t ws_size,
                              hipStream_t stream) {
    const float* node_embed = (const float*)d_in[0];
    const int*   eidx       = (const int*)  d_in[1];
    const float* attr       = (const float*)d_in[2];
    const float* W1         = (const float*)d_in[3];
    const float* b1         = (const float*)d_in[4];
    const float* gamma      = (const float*)d_in[5];
    const float* beta       = (const float*)d_in[6];
    const float* W2         = (const float*)d_in[7];
    const float* b2         = (const float*)d_in[8];
    const float* W3         = (const float*)d_in[9];
    const float* b3         = (const float*)d_in[10];
    float* out = (float*)d_out;

    if (ws_size < WS_NEED) return;

    char* ws = (char*)d_ws;
    ushort_t* atab = (ushort_t*)(ws + AT_OFF);
    ushort_t* w1f  = (ushort_t*)(ws + W1F_OFF);
    ushort_t* w2f  = (ushort_t*)(ws + W2F_OFF);

    cvt_wfrag<<<84, 64, 0, stream>>>(W1, W2, b2, w1f, w2f);
    build_atab<<<(NNODE + 511) / 512, 512, 0, stream>>>(node_embed, w1f, b1, atab);
    edge_mlp_mfma<<<GRID, 512, 0, stream>>>(atab, w2f, eidx, attr, W1,
                                            gamma, beta, W3, b3, out);
}

// Round 20
// 116.717 us; speedup vs baseline: 1.0522x; 1.0522x over previous
//
#include <hip/hip_runtime.h>
#include <hip/hip_bf16.h>
#include <hip/hip_fp16.h>

typedef __attribute__((ext_vector_type(8))) short short8;
typedef __attribute__((ext_vector_type(4))) float f32x4;
typedef _Float16 h2v __attribute__((ext_vector_type(2)));
typedef _Float16 h8v __attribute__((ext_vector_type(8)));
typedef unsigned short ushort_t;

namespace {

constexpr int H     = 128;
constexpr int E     = 1000000;
constexpr int NNODE = 100000;
constexpr int EB    = 512;                   // edges per tile (8 waves x 64)
constexpr int NTILE = (E + EB - 1) / EB;     // 1954
constexpr int GRID  = 256;                   // persistent: 1 block per CU
constexpr int TPB   = NTILE / GRID;          // 7
constexpr int REM   = NTILE - TPB * GRID;    // 162

// d_ws layout: atab fp16 [NNODE][256] (Ai+b1 | Aj), then W1(bf16)/W2(fp16) frag tables
constexpr size_t AT_OFF  = 0;
constexpr size_t AT_SZ   = (size_t)NNODE * 256 * 2;   // 51,200,000 B
constexpr size_t W1F_OFF = AT_SZ;
constexpr size_t W1F_SZ  = 64 * 64 * 8 * 2;           // 65536 B
constexpr size_t W2F_OFF = W1F_OFF + W1F_SZ;
constexpr size_t W2F_SZ  = 16 * 64 * 8 * 2;           // 16384 B (16 dense units; b2 via VALU)
constexpr size_t WS_NEED = W2F_OFF + W2F_SZ;

__device__ __forceinline__ ushort_t f2bf(float x) {
    unsigned u = __float_as_uint(x);
    return (ushort_t)((u + 0x7FFFu + ((u >> 16) & 1u)) >> 16);
}
__device__ __forceinline__ unsigned pkbf(float a, float b) {
    __hip_bfloat162 t = __float22bfloat162_rn(make_float2(a, b));
    return *reinterpret_cast<unsigned*>(&t);
}
__device__ __forceinline__ unsigned pkhf(float a, float b) {
    __half2 t = __float22half2_rn(make_float2(a, b));
    return *reinterpret_cast<unsigned*>(&t);
}
__device__ __forceinline__ int imin(int a, int b) { return a < b ? a : b; }

union FragU { int4 i; short8 s; };
union SlotU { short8 s; h2v h[4]; };
union H8U   { h8v v; h2v h[4]; int4 i; };
union U32H  { unsigned u; h2v h; };

typedef const __attribute__((address_space(1))) unsigned int* gptr_t;
typedef __attribute__((address_space(3))) unsigned int* lptr_t;

__device__ __forceinline__ void gload16(const void* g, void* l) {
    __builtin_amdgcn_global_load_lds((gptr_t)g, (lptr_t)l, 16, 0, 0);
}

// ---- prep 1: W1 (rows 0..255, bf16 for build_atab) / W2 (K=128, fp16, 16 units) ----
__global__ void cvt_wfrag(const float* __restrict__ W1, const float* __restrict__ W2,
                          ushort_t* __restrict__ w1f, ushort_t* __restrict__ w2f) {
    int u = blockIdx.x, l = threadIdx.x;
    int lo = l & 15, hi = l >> 4;
    if (u < 64) {
        int s = u >> 3, n = u & 7, col = n * 16 + lo;
#pragma unroll
        for (int j = 0; j < 8; ++j) {
            int kk = s * 32 + hi * 8 + j;
            w1f[(u * 64 + l) * 8 + j] = f2bf(W1[kk * 128 + col]);
        }
    } else {                            // W2: 4 K-steps x 4 N-tiles (rows 0..127 only)
        int u2 = u - 64;
        int s = u2 >> 2, n = u2 & 3, col = n * 16 + lo;
#pragma unroll
        for (int j = 0; j < 8; ++j) {
            int kk = s * 32 + hi * 8 + j;
            __half hh = __float2half_rn(W2[kk * 64 + col]);
            w2f[(u2 * 64 + l) * 8 + j] = *reinterpret_cast<ushort_t*>(&hh);
        }
    }
}

// ---- prep 2: A-tables. Ai = node.W1[0:128] + b1 (folded), Aj = node.W1[128:256] ----
struct PrepSm { ushort_t w1f[32768]; };

__global__ __launch_bounds__(512, 2)
void build_atab(const float* __restrict__ ne, const ushort_t* __restrict__ w1fg,
                const float* __restrict__ b1, ushort_t* __restrict__ atab) {
    __shared__ PrepSm sm;
    const int tid = threadIdx.x;
    {
        const uint4* s1 = reinterpret_cast<const uint4*>(w1fg);
        uint4*       d1 = reinterpret_cast<uint4*>(sm.w1f);
#pragma unroll
        for (int i = 0; i < 8; ++i) d1[i * 512 + tid] = s1[i * 512 + tid];
    }
    __syncthreads();

    const int wid = tid >> 6, lane = tid & 63;
    const int lo = lane & 15, hi = lane >> 4;
    const int nbase = blockIdx.x * 512 + wid * 64;
    const f32x4 z4 = {0.f, 0.f, 0.f, 0.f};

    short8 nf[4][4];
#pragma unroll
    for (int mt = 0; mt < 4; ++mt) {
        int node = imin(nbase + mt * 16 + lo, NNODE - 1);
        const float* row = ne + (size_t)node * H;
#pragma unroll
        for (int s = 0; s < 4; ++s) {
            f32x4 a = *reinterpret_cast<const f32x4*>(row + s * 32 + hi * 8);
            f32x4 b = *reinterpret_cast<const f32x4*>(row + s * 32 + hi * 8 + 4);
            FragU f;
            f.i = make_int4((int)pkbf(a[0], a[1]), (int)pkbf(a[2], a[3]),
                            (int)pkbf(b[0], b[1]), (int)pkbf(b[2], b[3]));
            nf[mt][s] = f.s;
        }
    }

#pragma unroll
    for (int X = 0; X < 2; ++X) {
        f32x4 acc[4][8];
        if (X == 0) {
#pragma unroll
            for (int n = 0; n < 8; ++n) {
                f32x4 b1v = *reinterpret_cast<const f32x4*>(b1 + n * 16 + hi * 4);
#pragma unroll
                for (int mt = 0; mt < 4; ++mt) acc[mt][n] = b1v;
            }
        } else {
#pragma unroll
            for (int mt = 0; mt < 4; ++mt)
#pragma unroll
                for (int n = 0; n < 8; ++n) acc[mt][n] = z4;
        }
#pragma unroll
        for (int s = 0; s < 4; ++s)
#pragma unroll
            for (int n = 0; n < 8; ++n) {
                short8 wa = *reinterpret_cast<const short8*>(
                    sm.w1f + (((X * 4 + s) * 8 + n) * 64 + lane) * 8);
#pragma unroll
                for (int mt = 0; mt < 4; ++mt)
                    acc[mt][n] = __builtin_amdgcn_mfma_f32_16x16x32_bf16(wa, nf[mt][s], acc[mt][n], 0, 0, 0);
            }
#pragma unroll
        for (int mt = 0; mt < 4; ++mt) {
            int node = nbase + mt * 16 + lo;
            if (node < NNODE) {
                ushort_t* dst = atab + (size_t)node * 256 + X * 128;
#pragma unroll
                for (int n = 0; n < 8; ++n) {
                    uint2 v = make_uint2(pkhf(acc[mt][n][0], acc[mt][n][1]),
                                         pkhf(acc[mt][n][2], acc[mt][n][3]));
                    *reinterpret_cast<uint2*>(dst + n * 16 + hi * 4) = v;
                }
            }
        }
    }
}

// ---- main persistent kernel: LDS-ring gather + packed-fp16 math + f16 MFMA ----
struct __align__(16) SmemT {
    char     gbuf[8][2][8192];           // 131072 B : per-wave 2-slot ring
    ushort_t w2f[8192];                  // 16384 B (fp16, 16 dense units)
    unsigned t0h[64], t1h[64], gh[64], bh[64];   // packed half2 params, 1 KB
    float    w3s[64], b2s[64];           // 512 B
};                                       // ~148.9 KB

// issue one subtile's 8 gathers (i then j slices) into `slotp`
#define GISSUE(slotp, iv, jv)                                                   \
    {                                                                           \
        const ushort_t* gi_ = atab + (size_t)(iv) * 256 + hi * 8;               \
        const ushort_t* gj_ = atab + (size_t)(jv) * 256 + 128 + hi * 8;         \
        char* lb_ = (slotp);                                                    \
        _Pragma("unroll")                                                       \
        for (int s_ = 0; s_ < 4; ++s_) gload16(gi_ + s_ * 32, lb_ + s_ * 1024); \
        _Pragma("unroll")                                                       \
        for (int s_ = 0; s_ < 4; ++s_) gload16(gj_ + s_ * 32, lb_ + 4096 + s_ * 1024); \
    }

// process one 16-edge subtile resident in `slotp`; then issue next gathers
#define SUBTILE(MT, slotp, WAITLIT, IV, JV)                                     \
    {                                                                           \
        asm volatile("s_waitcnt " WAITLIT ::: "memory");                        \
        __builtin_amdgcn_sched_barrier(0);                                      \
        const _Float16 axs = (_Float16)av[MT].x;                                \
        const _Float16 ays = (_Float16)av[MT].y;                                \
        const h2v ax2 = {axs, axs};                                             \
        const h2v ay2 = {ays, ays};                                             \
        float s1 = 0.f, s2v = 0.f;                                              \
        h2v x2[4][4];                                                           \
        _Pragma("unroll")                                                       \
        for (int s = 0; s < 4; ++s) {                                           \
            SlotU ui, uj;                                                       \
            ui.s = *reinterpret_cast<const short8*>((slotp) + s * 1024 + lane * 16);        \
            uj.s = *reinterpret_cast<const short8*>((slotp) + 4096 + s * 1024 + lane * 16); \
            uint4 t0p = *reinterpret_cast<const uint4*>(sm.t0h + s * 16 + hi * 4); \
            uint4 t1p = *reinterpret_cast<const uint4*>(sm.t1h + s * 16 + hi * 4); \
            const unsigned t0a[4] = {t0p.x, t0p.y, t0p.z, t0p.w};               \
            const unsigned t1a[4] = {t1p.x, t1p.y, t1p.z, t1p.w};               \
            _Pragma("unroll")                                                   \
            for (int p = 0; p < 4; ++p) {                                       \
                U32H w0; w0.u = t0a[p];                                         \
                U32H w1; w1.u = t1a[p];                                         \
                h2v t = ui.h[p] + uj.h[p];                                      \
                t = __builtin_elementwise_fma(ax2, w0.h, t);                    \
                t = __builtin_elementwise_fma(ay2, w1.h, t);                    \
                x2[s][p] = t;                                                   \
                s1  = __builtin_amdgcn_fdot2(t, one2, s1, false);               \
                s2v = __builtin_amdgcn_fdot2(t, t, s2v, false);                 \
            }                                                                   \
        }                                                                       \
        /* all slot reads complete before overwriting it (rule #18) */          \
        asm volatile("s_waitcnt lgkmcnt(0)" ::: "memory");                      \
        __builtin_amdgcn_sched_barrier(0);                                      \
        GISSUE(slotp, IV, JV);                                                  \
        __builtin_amdgcn_sched_barrier(0);                                      \
        s1 += __shfl_xor(s1, 16); s1 += __shfl_xor(s1, 32);                     \
        s2v += __shfl_xor(s2v, 16); s2v += __shfl_xor(s2v, 32);                 \
        float mean = s1 * (1.f / 128.f);                                        \
        float var  = s2v * (1.f / 128.f) - mean * mean;                         \
        float rstd = rsqrtf(var + 1e-5f);                                       \
        const _Float16 rs_ = (_Float16)rstd;                                    \
        const _Float16 cs_ = (_Float16)(-mean * rstd);                          \
        const h2v rs2 = {rs_, rs_};                                             \
        const h2v cs2 = {cs_, cs_};                                             \
        h8v hfr[4];                                                             \
        _Pragma("unroll")                                                       \
        for (int s = 0; s < 4; ++s) {                                           \
            uint4 gp = *reinterpret_cast<const uint4*>(sm.gh + s * 16 + hi * 4); \
            uint4 bp = *reinterpret_cast<const uint4*>(sm.bh + s * 16 + hi * 4); \
            const unsigned ga[4] = {gp.x, gp.y, gp.z, gp.w};                    \
            const unsigned ba[4] = {bp.x, bp.y, bp.z, bp.w};                    \
            H8U f;                                                              \
            _Pragma("unroll")                                                   \
            for (int p = 0; p < 4; ++p) {                                       \
                U32H g_; g_.u = ga[p];                                          \
                U32H b_; b_.u = ba[p];                                          \
                h2v t = __builtin_elementwise_fma(x2[s][p], rs2, cs2);          \
                t = __builtin_elementwise_fma(t, g_.h, b_.h);                   \
                t = __builtin_elementwise_max(t, zero2);                        \
                f.h[p] = t;                                                     \
            }                                                                   \
            hfr[s] = f.v;                                                       \
        }                                                                       \
        f32x4 a2[4];                                                            \
        _Pragma("unroll")                                                       \
        for (int n2 = 0; n2 < 4; ++n2) a2[n2] = zero4;                          \
        __builtin_amdgcn_s_setprio(1);                                          \
        _Pragma("unroll")                                                       \
        for (int s = 0; s < 4; ++s) {                                           \
            _Pragma("unroll")                                                   \
            for (int n2 = 0; n2 < 4; ++n2) {                                    \
                h8v wa = *reinterpret_cast<const h8v*>(sm.w2f + ((s * 4 + n2) * 64 + lane) * 8); \
                a2[n2] = __builtin_amdgcn_mfma_f32_16x16x32_f16(wa, hfr[s], a2[n2], 0, 0, 0); \
            }                                                                   \
        }                                                                       \
        __builtin_amdgcn_s_setprio(0);                                          \
        float part = 0.f;                                                       \
        _Pragma("unroll")                                                       \
        for (int n2 = 0; n2 < 4; ++n2) {                                        \
            f32x4 w3v = *reinterpret_cast<const f32x4*>(sm.w3s + n2 * 16 + hi * 4); \
            f32x4 b2v = *reinterpret_cast<const f32x4*>(sm.b2s + n2 * 16 + hi * 4); \
            _Pragma("unroll")                                                   \
            for (int r = 0; r < 4; ++r)                                         \
                part = fmaf(fmaxf(a2[n2][r] + b2v[r], 0.f), w3v[r], part);      \
        }                                                                       \
        part += __shfl_xor(part, 16);                                           \
        part += __shfl_xor(part, 32);                                           \
        if (hi == 0) {                                                          \
            int e = tb + (MT) * 16 + lo;                                        \
            if (e < E) out[e] = part + b3s;                                     \
        }                                                                       \
    }

__global__ __launch_bounds__(512, 2)
void edge_mlp_mfma(const ushort_t* __restrict__ atab,
                   const ushort_t* __restrict__ w2fg,
                   const int*      __restrict__ eidx,   // [2][E] int32
                   const float*    __restrict__ attr,   // [E][2]
                   const float*    __restrict__ W1,     // rows 256/257 (attr rows)
                   const float*    __restrict__ gamma_,
                   const float*    __restrict__ beta_,
                   const float*    __restrict__ b2,
                   const float*    __restrict__ W3,
                   const float*    __restrict__ b3,
                   float*          __restrict__ out) {
    __shared__ SmemT sm;
    const int tid = threadIdx.x;
    const int bid = blockIdx.x;

    {
        const uint4* s2 = reinterpret_cast<const uint4*>(w2fg);
        uint4*       d2 = reinterpret_cast<uint4*>(sm.w2f);
        for (int i = tid; i < 1024; i += 512) d2[i] = s2[i];
    }
    if (tid < 64) {
        sm.t0h[tid] = pkhf(W1[256 * H + 2 * tid], W1[256 * H + 2 * tid + 1]);
        sm.t1h[tid] = pkhf(W1[257 * H + 2 * tid], W1[257 * H + 2 * tid + 1]);
        sm.gh[tid]  = pkhf(gamma_[2 * tid], gamma_[2 * tid + 1]);
        sm.bh[tid]  = pkhf(beta_[2 * tid], beta_[2 * tid + 1]);
        sm.w3s[tid] = W3[tid];
        sm.b2s[tid] = b2[tid];
    }
    __syncthreads();   // drains all counters: clean vmcnt slate per wave

    const int wid = tid >> 6;
    const int lane = tid & 63;
    const int lo = lane & 15, hi = lane >> 4;
    const int ebl = wid * 64;
    const int nk = (bid < REM) ? TPB + 1 : TPB;
    char* slot0 = sm.gbuf[wid][0];
    char* slot1 = sm.gbuf[wid][1];
    const float2* attr2 = reinterpret_cast<const float2*>(attr);
    const float b3s = b3[0];
    const f32x4 zero4 = {0.f, 0.f, 0.f, 0.f};
    const h2v one2  = {(_Float16)1.f, (_Float16)1.f};
    const h2v zero2 = {(_Float16)0.f, (_Float16)0.f};

    int ci[4], cj[4], ni[4], nj[4];
    float2 av[4], avn[4];

    // ---- prologue: tile-0 indices (sync), g(0), g(1), tile-1 indices (async) ----
    {
        int tb0 = bid * EB + ebl;
#pragma unroll
        for (int mt = 0; mt < 4; ++mt) {
            int e = imin(tb0 + mt * 16 + lo, E - 1);
            ci[mt] = eidx[e]; cj[mt] = eidx[E + e];
            av[mt] = attr2[e];
        }
    }
    GISSUE(slot0, ci[0], cj[0]);
    GISSUE(slot1, ci[1], cj[1]);
    {
        int tb1 = (bid + imin(1, nk - 1) * GRID) * EB + ebl;
#pragma unroll
        for (int mt = 0; mt < 4; ++mt) {
            int e = imin(tb1 + mt * 16 + lo, E - 1);
            ni[mt] = eidx[e]; nj[mt] = eidx[E + e];
            avn[mt] = attr2[e];
        }
    }
    // vmcnt ledger at loop entry: [g0(8), g1(8), idx(12)] = 28 outstanding

    for (int k = 0; k < nk; ++k) {
        const int tb = (bid + k * GRID) * EB + ebl;

        // ST0: 28 out -> wait 20 drains g0.  reissue -> [g1, idx12, gC] = 28
        SUBTILE(0, slot0, "vmcnt(20)", ci[2], cj[2]);
        // ST1: wait 20 drains g1.            reissue -> [idx12, gC, gD] = 28
        SUBTILE(1, slot1, "vmcnt(20)", ci[3], cj[3]);
        // ST2: wait 8 drains idx12 + ALL of gC (R18 used 10: 2-deep race, fixed)
        SUBTILE(2, slot0, "vmcnt(8)", ni[0], nj[0]);
        // ST3: [gD, gE] = 16 -> wait 8 drains gD
        SUBTILE(3, slot1, "vmcnt(8)", ni[1], nj[1]);

        // rotate index state; load tile k+2's indices (12 VMEM, youngest in queue)
#pragma unroll
        for (int mt = 0; mt < 4; ++mt) { ci[mt] = ni[mt]; cj[mt] = nj[mt]; av[mt] = avn[mt]; }
        {
            int t2 = imin(k + 2, nk - 1);
            int tb2 = (bid + t2 * GRID) * EB + ebl;
#pragma unroll
            for (int mt = 0; mt < 4; ++mt) {
                int e = imin(tb2 + mt * 16 + lo, E - 1);
                ni[mt] = eidx[e]; nj[mt] = eidx[E + e];
                avn[mt] = attr2[e];
            }
        }
    }
}

} // namespace

extern "C" void kernel_launch(void* const* d_in, const int* in_sizes, int n_in,
                              void* d_out, int out_size, void* d_ws, size_t ws_size,
                              hipStream_t stream) {
    const float* node_embed = (const float*)d_in[0];
    const int*   eidx       = (const int*)  d_in[1];
    const float* attr       = (const float*)d_in[2];
    const float* W1         = (const float*)d_in[3];
    const float* b1         = (const float*)d_in[4];
    const float* gamma      = (const float*)d_in[5];
    const float* beta       = (const float*)d_in[6];
    const float* W2         = (const float*)d_in[7];
    const float* b2         = (const float*)d_in[8];
    const float* W3         = (const float*)d_in[9];
    const float* b3         = (const float*)d_in[10];
    float* out = (float*)d_out;

    if (ws_size < WS_NEED) return;

    char* ws = (char*)d_ws;
    ushort_t* atab = (ushort_t*)(ws + AT_OFF);
    ushort_t* w1f  = (ushort_t*)(ws + W1F_OFF);
    ushort_t* w2f  = (ushort_t*)(ws + W2F_OFF);

    cvt_wfrag<<<80, 64, 0, stream>>>(W1, W2, w1f, w2f);
    build_atab<<<(NNODE + 511) / 512, 512, 0, stream>>>(node_embed, w1f, b1, atab);
    edge_mlp_mfma<<<GRID, 512, 0, stream>>>(atab, w2f, eidx, attr, W1,
                                            gamma, beta, b2, W3, b3, out);
}

// Round 21
// 116.495 us; speedup vs baseline: 1.0542x; 1.0019x over previous
//
#include <hip/hip_runtime.h>
#include <hip/hip_bf16.h>
#include <hip/hip_fp16.h>

typedef __attribute__((ext_vector_type(8))) short short8;
typedef __attribute__((ext_vector_type(4))) float f32x4;
typedef _Float16 h2v __attribute__((ext_vector_type(2)));
typedef _Float16 h8v __attribute__((ext_vector_type(8)));
typedef unsigned short ushort_t;

namespace {

constexpr int H     = 128;
constexpr int E     = 1000000;
constexpr int NNODE = 100000;
constexpr int EB    = 512;                   // edges per tile (8 waves x 64)
constexpr int NTILE = (E + EB - 1) / EB;     // 1954
constexpr int GRID  = 256;                   // persistent: 1 block per CU
constexpr int TPB   = NTILE / GRID;          // 7
constexpr int REM   = NTILE - TPB * GRID;    // 162

// d_ws layout: atab fp16 [NNODE][256] (Ai+b1 | Aj), then W1(bf16)/W2(fp16) frag tables
constexpr size_t AT_OFF  = 0;
constexpr size_t AT_SZ   = (size_t)NNODE * 256 * 2;   // 51,200,000 B
constexpr size_t W1F_OFF = AT_SZ;
constexpr size_t W1F_SZ  = 64 * 64 * 8 * 2;           // 65536 B
constexpr size_t W2F_OFF = W1F_OFF + W1F_SZ;
constexpr size_t W2F_SZ  = 16 * 64 * 8 * 2;           // 16384 B (16 dense units; b2 via VALU)
constexpr size_t WS_NEED = W2F_OFF + W2F_SZ;

__device__ __forceinline__ ushort_t f2bf(float x) {
    unsigned u = __float_as_uint(x);
    return (ushort_t)((u + 0x7FFFu + ((u >> 16) & 1u)) >> 16);
}
__device__ __forceinline__ unsigned pkbf(float a, float b) {
    __hip_bfloat162 t = __float22bfloat162_rn(make_float2(a, b));
    return *reinterpret_cast<unsigned*>(&t);
}
__device__ __forceinline__ unsigned pkhf(float a, float b) {
    __half2 t = __float22half2_rn(make_float2(a, b));
    return *reinterpret_cast<unsigned*>(&t);
}
__device__ __forceinline__ int imin(int a, int b) { return a < b ? a : b; }

union FragU { int4 i; short8 s; };
union SlotU { short8 s; h2v h[4]; };
union H8U   { h8v v; h2v h[4]; int4 i; };
union U32H  { unsigned u; h2v h; };

typedef const __attribute__((address_space(1))) unsigned int* gptr_t;
typedef __attribute__((address_space(3))) unsigned int* lptr_t;

__device__ __forceinline__ void gload16(const void* g, void* l) {
    __builtin_amdgcn_global_load_lds((gptr_t)g, (lptr_t)l, 16, 0, 0);
}

// ---- prep 1: W1 (rows 0..255, bf16 for build_atab) / W2 (K=128, fp16, 16 units) ----
__global__ void cvt_wfrag(const float* __restrict__ W1, const float* __restrict__ W2,
                          ushort_t* __restrict__ w1f, ushort_t* __restrict__ w2f) {
    int u = blockIdx.x, l = threadIdx.x;
    int lo = l & 15, hi = l >> 4;
    if (u < 64) {
        int s = u >> 3, n = u & 7, col = n * 16 + lo;
#pragma unroll
        for (int j = 0; j < 8; ++j) {
            int kk = s * 32 + hi * 8 + j;
            w1f[(u * 64 + l) * 8 + j] = f2bf(W1[kk * 128 + col]);
        }
    } else {                            // W2: 4 K-steps x 4 N-tiles (rows 0..127 only)
        int u2 = u - 64;
        int s = u2 >> 2, n = u2 & 3, col = n * 16 + lo;
#pragma unroll
        for (int j = 0; j < 8; ++j) {
            int kk = s * 32 + hi * 8 + j;
            __half hh = __float2half_rn(W2[kk * 64 + col]);
            w2f[(u2 * 64 + l) * 8 + j] = *reinterpret_cast<ushort_t*>(&hh);
        }
    }
}

// ---- prep 2: A-tables. Ai = node.W1[0:128] + b1 (folded), Aj = node.W1[128:256].
//      R21: 391 blocks x 256 nodes (was 196 x 512) -- halves the per-block critical
//      path that was serializing the whole prep (196 blocks = 1 block/CU, wall =
//      one block's full stage+MFMA+store chain). Same numerics, same layout. ----
struct PrepSm { ushort_t w1f[32768]; };

__global__ __launch_bounds__(512, 2)
void build_atab(const float* __restrict__ ne, const ushort_t* __restrict__ w1fg,
                const float* __restrict__ b1, ushort_t* __restrict__ atab) {
    __shared__ PrepSm sm;
    const int tid = threadIdx.x;
    {
        const uint4* s1 = reinterpret_cast<const uint4*>(w1fg);
        uint4*       d1 = reinterpret_cast<uint4*>(sm.w1f);
#pragma unroll
        for (int i = 0; i < 8; ++i) d1[i * 512 + tid] = s1[i * 512 + tid];
    }
    __syncthreads();

    const int wid = tid >> 6, lane = tid & 63;
    const int lo = lane & 15, hi = lane >> 4;
    const int nbase = blockIdx.x * 256 + wid * 32;   // 2 subtiles of 16 nodes per wave
    const f32x4 z4 = {0.f, 0.f, 0.f, 0.f};

    short8 nf[2][4];
#pragma unroll
    for (int mt = 0; mt < 2; ++mt) {
        int node = imin(nbase + mt * 16 + lo, NNODE - 1);
        const float* row = ne + (size_t)node * H;
#pragma unroll
        for (int s = 0; s < 4; ++s) {
            f32x4 a = *reinterpret_cast<const f32x4*>(row + s * 32 + hi * 8);
            f32x4 b = *reinterpret_cast<const f32x4*>(row + s * 32 + hi * 8 + 4);
            FragU f;
            f.i = make_int4((int)pkbf(a[0], a[1]), (int)pkbf(a[2], a[3]),
                            (int)pkbf(b[0], b[1]), (int)pkbf(b[2], b[3]));
            nf[mt][s] = f.s;
        }
    }

#pragma unroll
    for (int X = 0; X < 2; ++X) {
        f32x4 acc[2][8];
        if (X == 0) {
#pragma unroll
            for (int n = 0; n < 8; ++n) {
                f32x4 b1v = *reinterpret_cast<const f32x4*>(b1 + n * 16 + hi * 4);
#pragma unroll
                for (int mt = 0; mt < 2; ++mt) acc[mt][n] = b1v;
            }
        } else {
#pragma unroll
            for (int mt = 0; mt < 2; ++mt)
#pragma unroll
                for (int n = 0; n < 8; ++n) acc[mt][n] = z4;
        }
#pragma unroll
        for (int s = 0; s < 4; ++s)
#pragma unroll
            for (int n = 0; n < 8; ++n) {
                short8 wa = *reinterpret_cast<const short8*>(
                    sm.w1f + (((X * 4 + s) * 8 + n) * 64 + lane) * 8);
#pragma unroll
                for (int mt = 0; mt < 2; ++mt)
                    acc[mt][n] = __builtin_amdgcn_mfma_f32_16x16x32_bf16(wa, nf[mt][s], acc[mt][n], 0, 0, 0);
            }
#pragma unroll
        for (int mt = 0; mt < 2; ++mt) {
            int node = nbase + mt * 16 + lo;
            if (node < NNODE) {
                ushort_t* dst = atab + (size_t)node * 256 + X * 128;
#pragma unroll
                for (int n = 0; n < 8; ++n) {
                    uint2 v = make_uint2(pkhf(acc[mt][n][0], acc[mt][n][1]),
                                         pkhf(acc[mt][n][2], acc[mt][n][3]));
                    *reinterpret_cast<uint2*>(dst + n * 16 + hi * 4) = v;
                }
            }
        }
    }
}

// ---- main persistent kernel: LDS-ring gather + packed-fp16 math + f16 MFMA ----
struct __align__(16) SmemT {
    char     gbuf[8][2][8192];           // 131072 B : per-wave 2-slot ring
    ushort_t w2f[8192];                  // 16384 B (fp16, 16 dense units)
    unsigned t0h[64], t1h[64], gh[64], bh[64];   // packed half2 params, 1 KB
    float    w3s[64], b2s[64];           // 512 B
};                                       // ~148.9 KB

// issue one subtile's 8 gathers (i then j slices) into `slotp`
#define GISSUE(slotp, iv, jv)                                                   \
    {                                                                           \
        const ushort_t* gi_ = atab + (size_t)(iv) * 256 + hi * 8;               \
        const ushort_t* gj_ = atab + (size_t)(jv) * 256 + 128 + hi * 8;         \
        char* lb_ = (slotp);                                                    \
        _Pragma("unroll")                                                       \
        for (int s_ = 0; s_ < 4; ++s_) gload16(gi_ + s_ * 32, lb_ + s_ * 1024); \
        _Pragma("unroll")                                                       \
        for (int s_ = 0; s_ < 4; ++s_) gload16(gj_ + s_ * 32, lb_ + 4096 + s_ * 1024); \
    }

// process one 16-edge subtile resident in `slotp`; then issue next gathers
#define SUBTILE(MT, slotp, WAITLIT, IV, JV)                                     \
    {                                                                           \
        asm volatile("s_waitcnt " WAITLIT ::: "memory");                        \
        __builtin_amdgcn_sched_barrier(0);                                      \
        const _Float16 axs = (_Float16)av[MT].x;                                \
        const _Float16 ays = (_Float16)av[MT].y;                                \
        const h2v ax2 = {axs, axs};                                             \
        const h2v ay2 = {ays, ays};                                             \
        float s1 = 0.f, s2v = 0.f;                                              \
        h2v x2[4][4];                                                           \
        _Pragma("unroll")                                                       \
        for (int s = 0; s < 4; ++s) {                                           \
            SlotU ui, uj;                                                       \
            ui.s = *reinterpret_cast<const short8*>((slotp) + s * 1024 + lane * 16);        \
            uj.s = *reinterpret_cast<const short8*>((slotp) + 4096 + s * 1024 + lane * 16); \
            uint4 t0p = *reinterpret_cast<const uint4*>(sm.t0h + s * 16 + hi * 4); \
            uint4 t1p = *reinterpret_cast<const uint4*>(sm.t1h + s * 16 + hi * 4); \
            const unsigned t0a[4] = {t0p.x, t0p.y, t0p.z, t0p.w};               \
            const unsigned t1a[4] = {t1p.x, t1p.y, t1p.z, t1p.w};               \
            _Pragma("unroll")                                                   \
            for (int p = 0; p < 4; ++p) {                                       \
                U32H w0; w0.u = t0a[p];                                         \
                U32H w1; w1.u = t1a[p];                                         \
                h2v t = ui.h[p] + uj.h[p];                                      \
                t = __builtin_elementwise_fma(ax2, w0.h, t);                    \
                t = __builtin_elementwise_fma(ay2, w1.h, t);                    \
                x2[s][p] = t;                                                   \
                s1  = __builtin_amdgcn_fdot2(t, one2, s1, false);               \
                s2v = __builtin_amdgcn_fdot2(t, t, s2v, false);                 \
            }                                                                   \
        }                                                                       \
        /* all slot reads complete before overwriting it (rule #18) */          \
        asm volatile("s_waitcnt lgkmcnt(0)" ::: "memory");                      \
        __builtin_amdgcn_sched_barrier(0);                                      \
        GISSUE(slotp, IV, JV);                                                  \
        __builtin_amdgcn_sched_barrier(0);                                      \
        s1 += __shfl_xor(s1, 16); s1 += __shfl_xor(s1, 32);                     \
        s2v += __shfl_xor(s2v, 16); s2v += __shfl_xor(s2v, 32);                 \
        float mean = s1 * (1.f / 128.f);                                        \
        float var  = s2v * (1.f / 128.f) - mean * mean;                         \
        float rstd = rsqrtf(var + 1e-5f);                                       \
        const _Float16 rs_ = (_Float16)rstd;                                    \
        const _Float16 cs_ = (_Float16)(-mean * rstd);                          \
        const h2v rs2 = {rs_, rs_};                                             \
        const h2v cs2 = {cs_, cs_};                                             \
        h8v hfr[4];                                                             \
        _Pragma("unroll")                                                       \
        for (int s = 0; s < 4; ++s) {                                           \
            uint4 gp = *reinterpret_cast<const uint4*>(sm.gh + s * 16 + hi * 4); \
            uint4 bp = *reinterpret_cast<const uint4*>(sm.bh + s * 16 + hi * 4); \
            const unsigned ga[4] = {gp.x, gp.y, gp.z, gp.w};                    \
            const unsigned ba[4] = {bp.x, bp.y, bp.z, bp.w};                    \
            H8U f;                                                              \
            _Pragma("unroll")                                                   \
            for (int p = 0; p < 4; ++p) {                                       \
                U32H g_; g_.u = ga[p];                                          \
                U32H b_; b_.u = ba[p];                                          \
                h2v t = __builtin_elementwise_fma(x2[s][p], rs2, cs2);          \
                t = __builtin_elementwise_fma(t, g_.h, b_.h);                   \
                t = __builtin_elementwise_max(t, zero2);                        \
                f.h[p] = t;                                                     \
            }                                                                   \
            hfr[s] = f.v;                                                       \
        }                                                                       \
        f32x4 a2[4];                                                            \
        _Pragma("unroll")                                                       \
        for (int n2 = 0; n2 < 4; ++n2) a2[n2] = zero4;                          \
        __builtin_amdgcn_s_setprio(1);                                          \
        _Pragma("unroll")                                                       \
        for (int s = 0; s < 4; ++s) {                                           \
            _Pragma("unroll")                                                   \
            for (int n2 = 0; n2 < 4; ++n2) {                                    \
                h8v wa = *reinterpret_cast<const h8v*>(sm.w2f + ((s * 4 + n2) * 64 + lane) * 8); \
                a2[n2] = __builtin_amdgcn_mfma_f32_16x16x32_f16(wa, hfr[s], a2[n2], 0, 0, 0); \
            }                                                                   \
        }                                                                       \
        __builtin_amdgcn_s_setprio(0);                                          \
        float part = 0.f;                                                       \
        _Pragma("unroll")                                                       \
        for (int n2 = 0; n2 < 4; ++n2) {                                        \
            f32x4 w3v = *reinterpret_cast<const f32x4*>(sm.w3s + n2 * 16 + hi * 4); \
            f32x4 b2v = *reinterpret_cast<const f32x4*>(sm.b2s + n2 * 16 + hi * 4); \
            _Pragma("unroll")                                                   \
            for (int r = 0; r < 4; ++r)                                         \
                part = fmaf(fmaxf(a2[n2][r] + b2v[r], 0.f), w3v[r], part);      \
        }                                                                       \
        part += __shfl_xor(part, 16);                                           \
        part += __shfl_xor(part, 32);                                           \
        if (hi == 0) {                                                          \
            int e = tb + (MT) * 16 + lo;                                        \
            if (e < E) out[e] = part + b3s;                                     \
        }                                                                       \
    }

__global__ __launch_bounds__(512, 2)
void edge_mlp_mfma(const ushort_t* __restrict__ atab,
                   const ushort_t* __restrict__ w2fg,
                   const int*      __restrict__ eidx,   // [2][E] int32
                   const float*    __restrict__ attr,   // [E][2]
                   const float*    __restrict__ W1,     // rows 256/257 (attr rows)
                   const float*    __restrict__ gamma_,
                   const float*    __restrict__ beta_,
                   const float*    __restrict__ b2,
                   const float*    __restrict__ W3,
                   const float*    __restrict__ b3,
                   float*          __restrict__ out) {
    __shared__ SmemT sm;
    const int tid = threadIdx.x;
    const int bid = blockIdx.x;

    {
        const uint4* s2 = reinterpret_cast<const uint4*>(w2fg);
        uint4*       d2 = reinterpret_cast<uint4*>(sm.w2f);
        for (int i = tid; i < 1024; i += 512) d2[i] = s2[i];
    }
    if (tid < 64) {
        sm.t0h[tid] = pkhf(W1[256 * H + 2 * tid], W1[256 * H + 2 * tid + 1]);
        sm.t1h[tid] = pkhf(W1[257 * H + 2 * tid], W1[257 * H + 2 * tid + 1]);
        sm.gh[tid]  = pkhf(gamma_[2 * tid], gamma_[2 * tid + 1]);
        sm.bh[tid]  = pkhf(beta_[2 * tid], beta_[2 * tid + 1]);
        sm.w3s[tid] = W3[tid];
        sm.b2s[tid] = b2[tid];
    }
    __syncthreads();   // drains all counters: clean vmcnt slate per wave

    const int wid = tid >> 6;
    const int lane = tid & 63;
    const int lo = lane & 15, hi = lane >> 4;
    const int ebl = wid * 64;
    const int nk = (bid < REM) ? TPB + 1 : TPB;
    char* slot0 = sm.gbuf[wid][0];
    char* slot1 = sm.gbuf[wid][1];
    const float2* attr2 = reinterpret_cast<const float2*>(attr);
    const float b3s = b3[0];
    const f32x4 zero4 = {0.f, 0.f, 0.f, 0.f};
    const h2v one2  = {(_Float16)1.f, (_Float16)1.f};
    const h2v zero2 = {(_Float16)0.f, (_Float16)0.f};

    int ci[4], cj[4], ni[4], nj[4];
    float2 av[4], avn[4];

    // ---- prologue: tile-0 indices (sync), g(0), g(1), tile-1 indices (async) ----
    {
        int tb0 = bid * EB + ebl;
#pragma unroll
        for (int mt = 0; mt < 4; ++mt) {
            int e = imin(tb0 + mt * 16 + lo, E - 1);
            ci[mt] = eidx[e]; cj[mt] = eidx[E + e];
            av[mt] = attr2[e];
        }
    }
    GISSUE(slot0, ci[0], cj[0]);
    GISSUE(slot1, ci[1], cj[1]);
    {
        int tb1 = (bid + imin(1, nk - 1) * GRID) * EB + ebl;
#pragma unroll
        for (int mt = 0; mt < 4; ++mt) {
            int e = imin(tb1 + mt * 16 + lo, E - 1);
            ni[mt] = eidx[e]; nj[mt] = eidx[E + e];
            avn[mt] = attr2[e];
        }
    }
    // vmcnt ledger at loop entry: [g0(8), g1(8), idx(12)] = 28 outstanding

    for (int k = 0; k < nk; ++k) {
        const int tb = (bid + k * GRID) * EB + ebl;

        // ST0: 28 out -> wait 20 drains g0.  reissue -> [g1, idx12, gC] = 28
        SUBTILE(0, slot0, "vmcnt(20)", ci[2], cj[2]);
        // ST1: wait 20 drains g1.            reissue -> [idx12, gC, gD] = 28
        SUBTILE(1, slot1, "vmcnt(20)", ci[3], cj[3]);
        // ST2: wait 8 drains idx12 + ALL of gC
        SUBTILE(2, slot0, "vmcnt(8)", ni[0], nj[0]);
        // ST3: [gD, gE] = 16 -> wait 8 drains gD
        SUBTILE(3, slot1, "vmcnt(8)", ni[1], nj[1]);

        // rotate index state; load tile k+2's indices (12 VMEM, youngest in queue)
#pragma unroll
        for (int mt = 0; mt < 4; ++mt) { ci[mt] = ni[mt]; cj[mt] = nj[mt]; av[mt] = avn[mt]; }
        {
            int t2 = imin(k + 2, nk - 1);
            int tb2 = (bid + t2 * GRID) * EB + ebl;
#pragma unroll
            for (int mt = 0; mt < 4; ++mt) {
                int e = imin(tb2 + mt * 16 + lo, E - 1);
                ni[mt] = eidx[e]; nj[mt] = eidx[E + e];
                avn[mt] = attr2[e];
            }
        }
    }
}

} // namespace

extern "C" void kernel_launch(void* const* d_in, const int* in_sizes, int n_in,
                              void* d_out, int out_size, void* d_ws, size_t ws_size,
                              hipStream_t stream) {
    const float* node_embed = (const float*)d_in[0];
    const int*   eidx       = (const int*)  d_in[1];
    const float* attr       = (const float*)d_in[2];
    const float* W1         = (const float*)d_in[3];
    const float* b1         = (const float*)d_in[4];
    const float* gamma      = (const float*)d_in[5];
    const float* beta       = (const float*)d_in[6];
    const float* W2         = (const float*)d_in[7];
    const float* b2         = (const float*)d_in[8];
    const float* W3         = (const float*)d_in[9];
    const float* b3         = (const float*)d_in[10];
    float* out = (float*)d_out;

    if (ws_size < WS_NEED) return;

    char* ws = (char*)d_ws;
    ushort_t* atab = (ushort_t*)(ws + AT_OFF);
    ushort_t* w1f  = (ushort_t*)(ws + W1F_OFF);
    ushort_t* w2f  = (ushort_t*)(ws + W2F_OFF);

    cvt_wfrag<<<80, 64, 0, stream>>>(W1, W2, w1f, w2f);
    build_atab<<<(NNODE + 255) / 256, 512, 0, stream>>>(node_embed, w1f, b1, atab);
    edge_mlp_mfma<<<GRID, 512, 0, stream>>>(atab, w2f, eidx, attr, W1,
                                            gamma, beta, b2, W3, b3, out);
}